// Round 1
// baseline (282.891 us; speedup 1.0000x reference)
//
#include <hip/hip_runtime.h>
#include <stdint.h>

#define B_ROWS 2048
#define C_CLS  9605
#define L_GRP  20
#define GM_BYTES (L_GRP * C_CLS) /* 192100 */
#define GID_PAD 9728             /* padded gid byte-table size, 4B-aligned */
#define WL_CAP  7168             /* whitelist entry capacity (actual: 1000) */
#define NEG_BIG -3.0e38f

/* ws layout:
   [0]          int  flag      (byte-vs-word layout probe result)
   [8]          int  wl_count  (atomic append counter for whitelist)
   [64]         u8   gid[GID_PAD]        gid[c] = group of class c, 0xFF none
   [64+GID_PAD] u32  wlist[WL_CAP]       entries: c | (l << 16)
*/

__device__ __forceinline__ float sigmoidf(float v) {
  return 1.0f / (1.0f + __expf(-v));
}

// our_rank_loss: d = x2-x1+0.05; s = sigmoid(10*d); d>0 ? 2*s : s
__device__ __forceinline__ float rank_loss(float x1, float x2) {
  float d = x2 - x1 + 0.05f;
  float s = 1.0f / (1.0f + __expf(-10.0f * d));
  return d > 0.0f ? 2.0f * s : s;
}

// order-preserving float<->uint mapping (unsigned atomicMax on floats)
__device__ __forceinline__ unsigned fmap(float f) {
  unsigned u = __float_as_uint(f);
  return (u & 0x80000000u) ? ~u : (u | 0x80000000u);
}
__device__ __forceinline__ float funmap(unsigned m) {
  unsigned u = (m & 0x80000000u) ? (m ^ 0x80000000u) : ~m;
  return __uint_as_float(u);
}

// Single-block: zero d_out + wl counter, 0xFF-init gid table, count nonzero
// bytes of group_mask's first L*C bytes (1000 -> byte layout; 250 int32 /
// 500 fp32 -> 4-byte layout).
__global__ void probe_init_kernel(const uint4* __restrict__ gm,
                                  unsigned char* __restrict__ ws,
                                  float* __restrict__ out,
                                  int* __restrict__ flag) {
  __shared__ int s_part[16];
  const int tid = threadIdx.x;  // 1024 threads
  if (tid == 0) {
    out[0] = 0.0f;
    *(int*)(ws + 8) = 0;
  }
  unsigned* gfill = (unsigned*)(ws + 64);
  for (int i = tid; i < GID_PAD / 4; i += 1024) gfill[i] = 0xFFFFFFFFu;
  int local = 0;
  const int nvec = GM_BYTES / 16;  // 12006 (tail = 4 bytes)
  for (int i = tid; i < nvec; i += 1024) {
    uint4 w = gm[i];
    unsigned a[4] = {w.x, w.y, w.z, w.w};
#pragma unroll
    for (int q = 0; q < 4; ++q) {
      local += ((a[q] & 0x000000FFu) != 0) + ((a[q] & 0x0000FF00u) != 0) +
               ((a[q] & 0x00FF0000u) != 0) + ((a[q] & 0xFF000000u) != 0);
    }
  }
  if (tid == 0) {
    const unsigned char* gb = (const unsigned char*)gm;
    for (int i = nvec * 16; i < GM_BYTES; ++i) local += (gb[i] != 0);
  }
#pragma unroll
  for (int off = 32; off; off >>= 1) local += __shfl_xor(local, off);
  if ((tid & 63) == 0) s_part[tid >> 6] = local;
  __syncthreads();
  if (tid == 0) {
    int tot = 0;
    for (int w = 0; w < 16; ++w) tot += s_part[w];
    *flag = tot;
  }
}

__global__ void build_gid_kernel(const void* gm, const int* __restrict__ flag,
                                 unsigned char* __restrict__ ws) {
  int i = blockIdx.x * blockDim.x + threadIdx.x;
  if (i >= GM_BYTES) return;
  const bool is_byte = (*flag > 600);
  bool m;
  if (is_byte) m = ((const unsigned char*)gm)[i] != 0;
  else         m = ((const unsigned int*)gm)[i] != 0u;
  if (m) {
    int l = i / C_CLS;
    int c = i - l * C_CLS;
    ws[64 + c] = (unsigned char)l;
    int p = atomicAdd((int*)(ws + 8), 1);
    if (p < WL_CAP)
      ((unsigned*)(ws + 64 + GID_PAD))[p] = (unsigned)c | ((unsigned)l << 16);
  }
}

__global__ __launch_bounds__(256, 4) void loss_kernel(
    const float* __restrict__ x, const int* __restrict__ y,
    const int* __restrict__ yn, const unsigned char* __restrict__ ws,
    float* __restrict__ out) {
  __shared__ unsigned s_gmax[L_GRP];
  __shared__ unsigned s_act, s_actn;
  __shared__ float s_wtop[4 * 11];
  const int tid = threadIdx.x;
  const int lane = tid & 63;
  const int wave = tid >> 6;
  const int row = blockIdx.x;  // grid = B_ROWS

  const size_t base = (size_t)row * C_CLS;
  const int mis = (int)(base & 3);
  const int peel = (4 - mis) & 3;
  const float* xr = x + base;
  const int* yr = y + base;
  const int* nr = yn + base;
  const unsigned char* gid = ws + 64;
  const unsigned* wlist = (const unsigned*)(ws + 64 + GID_PAD);
  int wl_n = *(const int*)(ws + 8);
  if (wl_n > WL_CAP) wl_n = WL_CAP;

  if (tid < L_GRP) s_gmax[tid] = 0u;  // 0 < fmap(any real float)
  if (tid == 0) { s_act = 0u; s_actn = 0u; }
  __syncthreads();

  // top-11 of raw x, descending. Init 0.0f is safe: thres clamps at
  // sigmoid>=0.5 <=> x>=0, so any 11th value <=0 is equivalent to 0.
  float t[11];
#pragma unroll
  for (int i = 0; i < 11; ++i) t[i] = 0.0f;
  unsigned actL = 0u, actnL = 0u;

  auto ins = [&](float v) {
    if (v > t[10]) {  // sorted insert
      float a = v;
#pragma unroll
      for (int i = 0; i < 11; ++i) {
        float hi = fmaxf(t[i], a); a = fminf(t[i], a); t[i] = hi;
      }
    }
  };
  auto edge = [&](int c) {  // scalar path for peel/tail elements
    ins(xr[c]);
    int yv = yr[c], nv = nr[c];
    if (yv | nv) {
      unsigned g = gid[c];
      if (g < L_GRP) {
        unsigned bit = 1u << g;
        if (yv) actL |= bit;
        if (nv) actnL |= bit;
      }
    }
  };

  if (tid < peel) edge(tid);
  const int nvec = (C_CLS - peel) >> 2;
  const int tail0 = peel + (nvec << 2);
  if (tid < C_CLS - tail0) edge(tail0 + tid);

  const float4* x4 = (const float4*)(xr + peel);
  const int4* y4 = (const int4*)(yr + peel);
  const int4* n4 = (const int4*)(nr + peel);

  // ---- Loop A: top-11 over x only (unroll 4 for MLP) ----
  {
    auto bodyA = [&](float4 a) {
      float am = fmaxf(fmaxf(a.x, a.y), fmaxf(a.z, a.w));
      if (am > t[10]) { ins(a.x); ins(a.y); ins(a.z); ins(a.w); }
    };
    int j = tid;
    for (; j + 768 < nvec; j += 1024) {
      float4 a = x4[j];
      float4 b = x4[j + 256];
      float4 c = x4[j + 512];
      float4 d = x4[j + 768];
      bodyA(a); bodyA(b); bodyA(c); bodyA(d);
    }
    for (; j < nvec; j += 256) bodyA(x4[j]);
  }

  // ---- Loop C: group max via compact whitelist (row x is L2-warm) ----
  for (int i = tid; i < wl_n; i += 256) {
    unsigned e = wlist[i];
    int c = (int)(e & 0xFFFFu);
    unsigned g = e >> 16;
    atomicMax(&s_gmax[g], fmap(xr[c]));
  }

  // ---- Loop B: active bits from y / yn (rare branch, unroll 2) ----
  {
    auto bodyB = [&](int j) {
      int4 yv = y4[j];
      int4 nv = n4[j];
      int any = yv.x | yv.y | yv.z | yv.w | nv.x | nv.y | nv.z | nv.w;
      if (any) {
        int c0 = peel + (j << 2);
        const int yq[4] = {yv.x, yv.y, yv.z, yv.w};
        const int nq[4] = {nv.x, nv.y, nv.z, nv.w};
#pragma unroll
        for (int q = 0; q < 4; ++q) {
          if (yq[q] | nq[q]) {
            unsigned g = gid[c0 + q];
            if (g < L_GRP) {
              unsigned bit = 1u << g;
              if (yq[q]) actL |= bit;
              if (nq[q]) actnL |= bit;
            }
          }
        }
      }
    };
    int j = tid;
    for (; j + 256 < nvec; j += 512) { bodyB(j); bodyB(j + 256); }
    if (j < nvec) bodyB(j);
  }

  if (actL) atomicOr(&s_act, actL);    // rare (~1 positive/row)
  if (actnL) atomicOr(&s_actn, actnL);

  // wave top-11: 11 rounds of max-extract from 64 sorted per-lane lists
  float cur = t[0];
  float mr[11];
#pragma unroll
  for (int r = 0; r < 11; ++r) {
    float m = cur;
#pragma unroll
    for (int off = 32; off; off >>= 1) m = fmaxf(m, __shfl_xor(m, off));
    mr[r] = m;
    if (r < 10) {
      unsigned long long b = __ballot(cur == m);
      int leader = (int)(__ffsll(b) - 1);
      if (lane == leader) {
#pragma unroll
        for (int i = 0; i < 10; ++i) t[i] = t[i + 1];
        t[10] = NEG_BIG;
        cur = t[0];
      }
    }
  }
  if (lane == 0) {
#pragma unroll
    for (int r = 0; r < 11; ++r) s_wtop[wave * 11 + r] = mr[r];
  }
  __syncthreads();  // also publishes s_gmax / s_act / s_actn

  if (wave == 0) {
    // merge 4 waves' sorted top-11 (44 candidates): 11 extract rounds
    float v = (lane < 44) ? s_wtop[lane] : NEG_BIG;
    float eleventh = NEG_BIG;
#pragma unroll
    for (int r = 0; r < 11; ++r) {
      float m = v;
#pragma unroll
      for (int off = 32; off; off >>= 1) m = fmaxf(m, __shfl_xor(m, off));
      eleventh = m;
      if (r < 10) {
        unsigned long long b = __ballot(v == m);
        int leader = (int)(__ffsll(b) - 1);
        if (lane == leader) v = NEG_BIG;
      }
    }

    const unsigned aL = s_act, anL = s_actn;
    const bool has_gt = (aL != 0u);
    const int g = has_gt ? (__ffs(aL) - 1) : 0;  // argmax of bool = first
    const float thres = fmaxf(sigmoidf(eleventh), 0.5f);

    float union_max = NEG_BIG, gt_sg = 0.0f, inc_max = NEG_BIG, inc_neg = 0.0f;
#pragma unroll
    for (int l = 0; l < L_GRP; ++l) {
      float sg = sigmoidf(funmap(s_gmax[l]));
      union_max = fmaxf(union_max, sg);
      if (l == g) gt_sg = sg; else inc_max = fmaxf(inc_max, sg);
      if ((anL >> l) & 1u) inc_neg = fmaxf(inc_neg, sg);
    }
    inc_max = fmaxf(inc_max, 0.0f);
    inc_neg = fmaxf(inc_neg, 0.0f);

    float loss;
    if (has_gt) {
      loss = rank_loss(gt_sg, thres);
      if (inc_max > 0.0f) loss += 0.5f * rank_loss(thres, inc_max);
      loss += 0.5f * rank_loss(thres, (inc_neg > 0.0f) ? inc_neg : inc_max);
    } else {
      loss = 0.5f * rank_loss(thres, union_max) + 0.5f * rank_loss(thres, inc_neg);
    }
    if (lane == 0) atomicAdd(out, loss);
  }
}

extern "C" void kernel_launch(void* const* d_in, const int* in_sizes, int n_in,
                              void* d_out, int out_size, void* d_ws, size_t ws_size,
                              hipStream_t stream) {
  (void)in_sizes; (void)n_in; (void)out_size; (void)ws_size;
  const float* x = (const float*)d_in[0];
  const int* y = (const int*)d_in[1];
  const int* yn = (const int*)d_in[2];
  const void* gm = d_in[3];

  int* flag = (int*)d_ws;
  unsigned char* ws = (unsigned char*)d_ws;

  probe_init_kernel<<<1, 1024, 0, stream>>>((const uint4*)gm, ws,
                                            (float*)d_out, flag);
  build_gid_kernel<<<(GM_BYTES + 255) / 256, 256, 0, stream>>>(gm, flag, ws);
  loss_kernel<<<B_ROWS, 256, 0, stream>>>(x, y, yn, ws, (float*)d_out);
}

// Round 2
// 258.363 us; speedup vs baseline: 1.0949x; 1.0949x over previous
//
#include <hip/hip_runtime.h>
#include <stdint.h>

#define B_ROWS 2048
#define C_CLS  9605
#define L_GRP  20
#define GM_BYTES (L_GRP * C_CLS) /* 192100 */
#define REPSTRIDE 9728           /* multiple of 4, > C_CLS */
#define NEG_BIG -3.0e38f

__device__ __forceinline__ float sigmoidf(float v) {
  return 1.0f / (1.0f + __expf(-v));
}

// our_rank_loss: d = x2-x1+0.05; s = sigmoid(10*d); d>0 ? 2*s : s
__device__ __forceinline__ float rank_loss(float x1, float x2) {
  float d = x2 - x1 + 0.05f;
  float s = 1.0f / (1.0f + __expf(-10.0f * d));
  return d > 0.0f ? 2.0f * s : s;
}

// order-preserving float<->uint mapping (unsigned atomicMax on floats)
__device__ __forceinline__ unsigned fmap(float f) {
  unsigned u = __float_as_uint(f);
  return (u & 0x80000000u) ? ~u : (u | 0x80000000u);
}
__device__ __forceinline__ float funmap(unsigned m) {
  unsigned u = (m & 0x80000000u) ? (m ^ 0x80000000u) : ~m;
  return __uint_as_float(u);
}

// ws layout: [0..63] flag ; [64 ...] 4 byte-shifted gid copies, copy m at
// ws + 64 + m*REPSTRIDE + m  (so (copy_m + peel) is 4B-aligned for rows with
// (row*C)&3 == m). Single-block fused kernel: zero d_out, 0xFF-init the gid
// region, vector-count nonzero bytes of group_mask's first L*C bytes
// (1000 -> byte/bool layout; 250 int32 / 500 fp32 -> 4-byte layout).
__global__ void probe_init_kernel(const uint4* __restrict__ gm,
                                  unsigned char* __restrict__ ws,
                                  float* __restrict__ out,
                                  int* __restrict__ flag) {
  __shared__ int s_part[16];
  const int tid = threadIdx.x;  // 1024 threads
  if (tid == 0) out[0] = 0.0f;
  const int initbytes = 3 * REPSTRIDE + C_CLS + 16;
  for (int i = tid; i < initbytes; i += 1024) ws[64 + i] = 0xFF;
  int local = 0;
  const int nvec = GM_BYTES / 16;  // 12006 (tail = 4 bytes)
  for (int i = tid; i < nvec; i += 1024) {
    uint4 w = gm[i];
    unsigned a[4] = {w.x, w.y, w.z, w.w};
#pragma unroll
    for (int q = 0; q < 4; ++q) {
      local += ((a[q] & 0x000000FFu) != 0) + ((a[q] & 0x0000FF00u) != 0) +
               ((a[q] & 0x00FF0000u) != 0) + ((a[q] & 0xFF000000u) != 0);
    }
  }
  if (tid == 0) {
    const unsigned char* gb = (const unsigned char*)gm;
    for (int i = nvec * 16; i < GM_BYTES; ++i) local += (gb[i] != 0);
  }
#pragma unroll
  for (int off = 32; off; off >>= 1) local += __shfl_xor(local, off);
  if ((tid & 63) == 0) s_part[tid >> 6] = local;
  __syncthreads();
  if (tid == 0) {
    int tot = 0;
    for (int w = 0; w < 16; ++w) tot += s_part[w];
    *flag = tot;
  }
}

__global__ void build_gid_kernel(const void* gm, const int* __restrict__ flag,
                                 unsigned char* __restrict__ ws) {
  int i = blockIdx.x * blockDim.x + threadIdx.x;
  if (i >= GM_BYTES) return;
  const bool is_byte = (*flag > 600);
  bool m;
  if (is_byte) m = ((const unsigned char*)gm)[i] != 0;
  else         m = ((const unsigned int*)gm)[i] != 0u;
  if (m) {
    int l = i / C_CLS;
    int c = i - l * C_CLS;
    unsigned char* base = ws + 64;
#pragma unroll
    for (int r = 0; r < 4; ++r) base[r * REPSTRIDE + r + c] = (unsigned char)l;
  }
}

__global__ __launch_bounds__(256, 4) void loss_kernel(
    const float* __restrict__ x, const int* __restrict__ y,
    const int* __restrict__ yn, const unsigned char* __restrict__ ws64,
    float* __restrict__ out) {
  __shared__ unsigned s_gmax[L_GRP];
  __shared__ unsigned s_act, s_actn;
  __shared__ float s_wtop[4 * 11];
  const int tid = threadIdx.x;
  const int lane = tid & 63;
  const int wave = tid >> 6;
  const int row = blockIdx.x;  // grid = B_ROWS

  const size_t base = (size_t)row * C_CLS;
  const int mis = (int)(base & 3);
  const int peel = (4 - mis) & 3;
  const float* xr = x + base;
  const int* yr = y + base;
  const int* nr = yn + base;
  const unsigned char* gidc = ws64 + mis * REPSTRIDE + mis;  // gidc[c]=gid[c]

  if (tid < L_GRP) s_gmax[tid] = 0u;  // 0 < fmap(any real float)
  if (tid == 0) { s_act = 0u; s_actn = 0u; }
  __syncthreads();

  // top-11 of raw x, descending. Init 0.0f is safe: thres clamps at
  // sigmoid>=0.5 <=> x>=0, so any 11th value <=0 is equivalent to 0.
  float t[11];
#pragma unroll
  for (int i = 0; i < 11; ++i) t[i] = 0.0f;
  unsigned actL = 0u, actnL = 0u;

  auto ins = [&](float v) {
    if (v > t[10]) {  // sorted insert
      float a = v;
#pragma unroll
      for (int i = 0; i < 11; ++i) {
        float hi = fmaxf(t[i], a); a = fminf(t[i], a); t[i] = hi;
      }
    }
  };
  // lazy group max: plain LDS read, atomic only if improving
  auto gmax_upd = [&](unsigned gk, float v) {
    unsigned fm = fmap(v);
    if (fm > s_gmax[gk]) atomicMax(&s_gmax[gk], fm);
  };
  auto edge = [&](int c) {  // scalar path for peel/tail elements
    float v = xr[c];
    ins(v);
    unsigned gk = gidc[c];
    if (gk < L_GRP) {
      gmax_upd(gk, v);
      unsigned bit = 1u << gk;
      if (yr[c] != 0) actL |= bit;
      if (nr[c] != 0) actnL |= bit;
    }
  };

  if (tid < peel) edge(tid);
  const int nvec = (C_CLS - peel) >> 2;
  const int tail0 = peel + (nvec << 2);
  if (tid < C_CLS - tail0) edge(tail0 + tid);

  const float4* x4 = (const float4*)(xr + peel);
  const int4* y4 = (const int4*)(yr + peel);
  const int4* n4 = (const int4*)(nr + peel);
  const unsigned* g4 = (const unsigned*)(gidc + peel);

  // ---- fused main loop, explicit 1-stage software pipeline ----
  int j = tid;
  if (j < nvec) {
    float4 xa = x4[j];
    int4 ya = y4[j];
    int4 na = n4[j];
    unsigned ga = g4[j];
    for (;;) {
      const int jn = j + 256;
      const bool more = jn < nvec;
      float4 xb; int4 yb, nb; unsigned gb;
      if (more) {  // prefetch next stage BEFORE touching current regs
        xb = x4[jn]; yb = y4[jn]; nb = n4[jn]; gb = g4[jn];
      }

      // group-max path (~34% of stages have a whitelisted lane-element)
      if (ga != 0xFFFFFFFFu) {
        unsigned g0 = ga & 0xFFu, g1 = (ga >> 8) & 0xFFu,
                 g2 = (ga >> 16) & 0xFFu, g3 = ga >> 24;
        if (g0 < L_GRP) gmax_upd(g0, xa.x);
        if (g1 < L_GRP) gmax_upd(g1, xa.y);
        if (g2 < L_GRP) gmax_upd(g2, xa.z);
        if (g3 < L_GRP) gmax_upd(g3, xa.w);
      }
      // active-bits path (rare: ~0.1% density)
      if (ya.x | ya.y | ya.z | ya.w | na.x | na.y | na.z | na.w) {
        const int yq[4] = {ya.x, ya.y, ya.z, ya.w};
        const int nq[4] = {na.x, na.y, na.z, na.w};
        const unsigned gq[4] = {ga & 0xFFu, (ga >> 8) & 0xFFu,
                                (ga >> 16) & 0xFFu, ga >> 24};
#pragma unroll
        for (int q = 0; q < 4; ++q) {
          if ((yq[q] | nq[q]) && gq[q] < L_GRP) {
            unsigned bit = 1u << gq[q];
            if (yq[q]) actL |= bit;
            if (nq[q]) actnL |= bit;
          }
        }
      }
      // top-11 insert, pre-gated on the 4-max
      float am = fmaxf(fmaxf(xa.x, xa.y), fmaxf(xa.z, xa.w));
      if (am > t[10]) { ins(xa.x); ins(xa.y); ins(xa.z); ins(xa.w); }

      if (!more) break;
      j = jn;
      xa = xb; ya = yb; na = nb; ga = gb;
    }
  }

  if (actL) atomicOr(&s_act, actL);    // rare (~1 positive/row)
  if (actnL) atomicOr(&s_actn, actnL);

  // wave top-11: 11 rounds of max-extract from 64 sorted per-lane lists
  float cur = t[0];
  float mr[11];
#pragma unroll
  for (int r = 0; r < 11; ++r) {
    float m = cur;
#pragma unroll
    for (int off = 32; off; off >>= 1) m = fmaxf(m, __shfl_xor(m, off));
    mr[r] = m;
    if (r < 10) {
      unsigned long long b = __ballot(cur == m);
      int leader = (int)(__ffsll(b) - 1);
      if (lane == leader) {
#pragma unroll
        for (int i = 0; i < 10; ++i) t[i] = t[i + 1];
        t[10] = NEG_BIG;
        cur = t[0];
      }
    }
  }
  if (lane == 0) {
#pragma unroll
    for (int r = 0; r < 11; ++r) s_wtop[wave * 11 + r] = mr[r];
  }
  __syncthreads();  // also publishes s_gmax / s_act / s_actn

  if (wave == 0) {
    // merge 4 waves' sorted top-11 (44 candidates): 11 extract rounds
    float v = (lane < 44) ? s_wtop[lane] : NEG_BIG;
    float eleventh = NEG_BIG;
#pragma unroll
    for (int r = 0; r < 11; ++r) {
      float m = v;
#pragma unroll
      for (int off = 32; off; off >>= 1) m = fmaxf(m, __shfl_xor(m, off));
      eleventh = m;
      if (r < 10) {
        unsigned long long b = __ballot(v == m);
        int leader = (int)(__ffsll(b) - 1);
        if (lane == leader) v = NEG_BIG;
      }
    }

    const unsigned aL = s_act, anL = s_actn;
    const bool has_gt = (aL != 0u);
    const int g = has_gt ? (__ffs(aL) - 1) : 0;  // argmax of bool = first
    const float thres = fmaxf(sigmoidf(eleventh), 0.5f);

    float union_max = NEG_BIG, gt_sg = 0.0f, inc_max = NEG_BIG, inc_neg = 0.0f;
#pragma unroll
    for (int l = 0; l < L_GRP; ++l) {
      float sg = sigmoidf(funmap(s_gmax[l]));
      union_max = fmaxf(union_max, sg);
      if (l == g) gt_sg = sg; else inc_max = fmaxf(inc_max, sg);
      if ((anL >> l) & 1u) inc_neg = fmaxf(inc_neg, sg);
    }
    inc_max = fmaxf(inc_max, 0.0f);
    inc_neg = fmaxf(inc_neg, 0.0f);

    float loss;
    if (has_gt) {
      loss = rank_loss(gt_sg, thres);
      if (inc_max > 0.0f) loss += 0.5f * rank_loss(thres, inc_max);
      loss += 0.5f * rank_loss(thres, (inc_neg > 0.0f) ? inc_neg : inc_max);
    } else {
      loss = 0.5f * rank_loss(thres, union_max) + 0.5f * rank_loss(thres, inc_neg);
    }
    if (lane == 0) atomicAdd(out, loss);
  }
}

extern "C" void kernel_launch(void* const* d_in, const int* in_sizes, int n_in,
                              void* d_out, int out_size, void* d_ws, size_t ws_size,
                              hipStream_t stream) {
  (void)in_sizes; (void)n_in; (void)out_size; (void)ws_size;
  const float* x = (const float*)d_in[0];
  const int* y = (const int*)d_in[1];
  const int* yn = (const int*)d_in[2];
  const void* gm = d_in[3];

  int* flag = (int*)d_ws;
  unsigned char* ws = (unsigned char*)d_ws;
  unsigned char* ws64 = ws + 64;

  probe_init_kernel<<<1, 1024, 0, stream>>>((const uint4*)gm, ws,
                                            (float*)d_out, flag);
  build_gid_kernel<<<(GM_BYTES + 255) / 256, 256, 0, stream>>>(gm, flag, ws);
  loss_kernel<<<B_ROWS, 256, 0, stream>>>(x, y, yn, ws64, (float*)d_out);
}

// Round 3
// 256.214 us; speedup vs baseline: 1.1041x; 1.0084x over previous
//
#include <hip/hip_runtime.h>
#include <stdint.h>

#define B_ROWS 2048
#define C_CLS  9605
#define L_GRP  20
#define GM_BYTES (L_GRP * C_CLS) /* 192100 */
#define REPSTRIDE 9728           /* multiple of 4, > C_CLS */
#define GID_REGION (4 * REPSTRIDE)    /* 38912 B of gid copies at ws+64 */
#define PARTIAL_OFF (64 + GID_REGION) /* 38976, 4B-aligned: float[B_ROWS] */
#define NEG_BIG -3.0e38f

__device__ __forceinline__ float sigmoidf(float v) {
  return 1.0f / (1.0f + __expf(-v));
}

// our_rank_loss: d = x2-x1+0.05; s = sigmoid(10*d); d>0 ? 2*s : s
__device__ __forceinline__ float rank_loss(float x1, float x2) {
  float d = x2 - x1 + 0.05f;
  float s = 1.0f / (1.0f + __expf(-10.0f * d));
  return d > 0.0f ? 2.0f * s : s;
}

// order-preserving float<->uint mapping (unsigned atomicMax on floats)
__device__ __forceinline__ unsigned fmap(float f) {
  unsigned u = __float_as_uint(f);
  return (u & 0x80000000u) ? ~u : (u | 0x80000000u);
}
__device__ __forceinline__ float funmap(unsigned m) {
  unsigned u = (m & 0x80000000u) ? (m ^ 0x80000000u) : ~m;
  return __uint_as_float(u);
}

// ws layout: [0..63] flag ; [64 ...] 4 byte-shifted gid copies, copy m at
// ws + 64 + m*REPSTRIDE + m ; [PARTIAL_OFF ...] float partial[B_ROWS].
// Single-block kernel: zero d_out, 0xFF-init the gid region (uint4 fills),
// vector-count nonzero bytes of group_mask's first L*C bytes
// (1000 -> byte/bool layout; 250 int32 / 500 fp32 -> 4-byte layout).
__global__ void probe_init_kernel(const uint4* __restrict__ gm,
                                  unsigned char* __restrict__ ws,
                                  float* __restrict__ out,
                                  int* __restrict__ flag) {
  __shared__ int s_part[16];
  const int tid = threadIdx.x;  // 1024 threads
  if (tid == 0) out[0] = 0.0f;
  uint4* gfill = (uint4*)(ws + 64);  // ws+64 is 16B-aligned
  const unsigned F = 0xFFFFFFFFu;
  for (int i = tid; i < GID_REGION / 16; i += 1024)
    gfill[i] = make_uint4(F, F, F, F);
  int local = 0;
  const int nvec = GM_BYTES / 16;  // 12006 (tail = 4 bytes)
  for (int i = tid; i < nvec; i += 1024) {
    uint4 w = gm[i];
    unsigned a[4] = {w.x, w.y, w.z, w.w};
#pragma unroll
    for (int q = 0; q < 4; ++q) {
      local += ((a[q] & 0x000000FFu) != 0) + ((a[q] & 0x0000FF00u) != 0) +
               ((a[q] & 0x00FF0000u) != 0) + ((a[q] & 0xFF000000u) != 0);
    }
  }
  if (tid == 0) {
    const unsigned char* gb = (const unsigned char*)gm;
    for (int i = nvec * 16; i < GM_BYTES; ++i) local += (gb[i] != 0);
  }
#pragma unroll
  for (int off = 32; off; off >>= 1) local += __shfl_xor(local, off);
  if ((tid & 63) == 0) s_part[tid >> 6] = local;
  __syncthreads();
  if (tid == 0) {
    int tot = 0;
    for (int w = 0; w < 16; ++w) tot += s_part[w];
    *flag = tot;
  }
}

__global__ void build_gid_kernel(const void* gm, const int* __restrict__ flag,
                                 unsigned char* __restrict__ ws) {
  int i = blockIdx.x * blockDim.x + threadIdx.x;
  if (i >= GM_BYTES) return;
  const bool is_byte = (*flag > 600);
  bool m;
  if (is_byte) m = ((const unsigned char*)gm)[i] != 0;
  else         m = ((const unsigned int*)gm)[i] != 0u;
  if (m) {
    int l = i / C_CLS;
    int c = i - l * C_CLS;
    unsigned char* base = ws + 64;
#pragma unroll
    for (int r = 0; r < 4; ++r) base[r * REPSTRIDE + r + c] = (unsigned char)l;
  }
}

__global__ __launch_bounds__(256, 4) void loss_kernel(
    const float* __restrict__ x, const int* __restrict__ y,
    const int* __restrict__ yn, const unsigned char* __restrict__ ws64,
    float* __restrict__ partial) {
  __shared__ unsigned s_gmax[L_GRP];
  __shared__ unsigned s_act, s_actn;
  __shared__ float s_wtop[4 * 11];
  const int tid = threadIdx.x;
  const int lane = tid & 63;
  const int wave = tid >> 6;
  const int row = blockIdx.x;  // grid = B_ROWS

  const size_t base = (size_t)row * C_CLS;
  const int mis = (int)(base & 3);
  const int peel = (4 - mis) & 3;
  const float* xr = x + base;
  const int* yr = y + base;
  const int* nr = yn + base;
  const unsigned char* gidc = ws64 + mis * REPSTRIDE + mis;  // gidc[c]=gid[c]

  if (tid < L_GRP) s_gmax[tid] = 0u;  // 0 < fmap(any real float)
  if (tid == 0) { s_act = 0u; s_actn = 0u; }
  __syncthreads();

  // top-11 of raw x, descending. Init 0.0f is safe: thres clamps at
  // sigmoid>=0.5 <=> x>=0, so any 11th value <=0 is equivalent to 0.
  float t[11];
#pragma unroll
  for (int i = 0; i < 11; ++i) t[i] = 0.0f;
  unsigned actL = 0u, actnL = 0u;

  auto ins = [&](float v) {
    if (v > t[10]) {  // sorted insert
      float a = v;
#pragma unroll
      for (int i = 0; i < 11; ++i) {
        float hi = fmaxf(t[i], a); a = fminf(t[i], a); t[i] = hi;
      }
    }
  };
  // lazy group max: plain LDS read, atomic only if improving (monotone up,
  // so a stale read is never too high -> safe)
  auto gmax_upd = [&](unsigned gk, float v) {
    unsigned fm = fmap(v);
    if (fm > s_gmax[gk]) atomicMax(&s_gmax[gk], fm);
  };
  auto edge = [&](int c) {  // scalar path for peel/tail elements
    float v = xr[c];
    ins(v);
    unsigned gk = gidc[c];
    if (gk < L_GRP) {
      gmax_upd(gk, v);
      unsigned bit = 1u << gk;
      if (yr[c] != 0) actL |= bit;
      if (nr[c] != 0) actnL |= bit;
    }
  };

  if (tid < peel) edge(tid);
  const int nvec = (C_CLS - peel) >> 2;
  const int tail0 = peel + (nvec << 2);
  if (tid < C_CLS - tail0) edge(tail0 + tid);

  const float4* x4 = (const float4*)(xr + peel);
  const int4* y4 = (const int4*)(yr + peel);
  const int4* n4 = (const int4*)(nr + peel);
  const unsigned* g4 = (const unsigned*)(gidc + peel);

  // ---- fused main loop: simple form, compiler schedules the loads ----
  for (int j = tid; j < nvec; j += 256) {
    float4 xv = x4[j];
    int4 yv = y4[j];
    int4 nv = n4[j];
    unsigned gw = g4[j];

    // group-max path (~34% of quads contain a whitelisted element)
    if (gw != 0xFFFFFFFFu) {
      unsigned g0 = gw & 0xFFu, g1 = (gw >> 8) & 0xFFu,
               g2 = (gw >> 16) & 0xFFu, g3 = gw >> 24;
      if (g0 < L_GRP) gmax_upd(g0, xv.x);
      if (g1 < L_GRP) gmax_upd(g1, xv.y);
      if (g2 < L_GRP) gmax_upd(g2, xv.z);
      if (g3 < L_GRP) gmax_upd(g3, xv.w);
    }
    // active-bits path (rare: ~0.1% density)
    if (yv.x | yv.y | yv.z | yv.w | nv.x | nv.y | nv.z | nv.w) {
      const int yq[4] = {yv.x, yv.y, yv.z, yv.w};
      const int nq[4] = {nv.x, nv.y, nv.z, nv.w};
      const unsigned gq[4] = {gw & 0xFFu, (gw >> 8) & 0xFFu,
                              (gw >> 16) & 0xFFu, gw >> 24};
#pragma unroll
      for (int q = 0; q < 4; ++q) {
        if ((yq[q] | nq[q]) && gq[q] < L_GRP) {
          unsigned bit = 1u << gq[q];
          if (yq[q]) actL |= bit;
          if (nq[q]) actnL |= bit;
        }
      }
    }
    // top-11 insert, pre-gated on the 4-max
    float am = fmaxf(fmaxf(xv.x, xv.y), fmaxf(xv.z, xv.w));
    if (am > t[10]) { ins(xv.x); ins(xv.y); ins(xv.z); ins(xv.w); }
  }

  if (actL) atomicOr(&s_act, actL);    // rare (~1 positive/row)
  if (actnL) atomicOr(&s_actn, actnL);

  // wave top-11: 11 rounds of max-extract from 64 sorted per-lane lists
  float cur = t[0];
  float mr[11];
#pragma unroll
  for (int r = 0; r < 11; ++r) {
    float m = cur;
#pragma unroll
    for (int off = 32; off; off >>= 1) m = fmaxf(m, __shfl_xor(m, off));
    mr[r] = m;
    if (r < 10) {
      unsigned long long b = __ballot(cur == m);
      int leader = (int)(__ffsll(b) - 1);
      if (lane == leader) {
#pragma unroll
        for (int i = 0; i < 10; ++i) t[i] = t[i + 1];
        t[10] = NEG_BIG;
        cur = t[0];
      }
    }
  }
  if (lane == 0) {
#pragma unroll
    for (int r = 0; r < 11; ++r) s_wtop[wave * 11 + r] = mr[r];
  }
  __syncthreads();  // also publishes s_gmax / s_act / s_actn

  if (wave == 0) {
    // merge 4 waves' sorted top-11 (44 candidates): 11 extract rounds
    float v = (lane < 44) ? s_wtop[lane] : NEG_BIG;
    float eleventh = NEG_BIG;
#pragma unroll
    for (int r = 0; r < 11; ++r) {
      float m = v;
#pragma unroll
      for (int off = 32; off; off >>= 1) m = fmaxf(m, __shfl_xor(m, off));
      eleventh = m;
      if (r < 10) {
        unsigned long long b = __ballot(v == m);
        int leader = (int)(__ffsll(b) - 1);
        if (lane == leader) v = NEG_BIG;
      }
    }

    const unsigned aL = s_act, anL = s_actn;
    const bool has_gt = (aL != 0u);
    const int g = has_gt ? (__ffs(aL) - 1) : 0;  // argmax of bool = first
    const float thres = fmaxf(sigmoidf(eleventh), 0.5f);

    float union_max = NEG_BIG, gt_sg = 0.0f, inc_max = NEG_BIG, inc_neg = 0.0f;
#pragma unroll
    for (int l = 0; l < L_GRP; ++l) {
      float sg = sigmoidf(funmap(s_gmax[l]));
      union_max = fmaxf(union_max, sg);
      if (l == g) gt_sg = sg; else inc_max = fmaxf(inc_max, sg);
      if ((anL >> l) & 1u) inc_neg = fmaxf(inc_neg, sg);
    }
    inc_max = fmaxf(inc_max, 0.0f);
    inc_neg = fmaxf(inc_neg, 0.0f);

    float loss;
    if (has_gt) {
      loss = rank_loss(gt_sg, thres);
      if (inc_max > 0.0f) loss += 0.5f * rank_loss(thres, inc_max);
      loss += 0.5f * rank_loss(thres, (inc_neg > 0.0f) ? inc_neg : inc_max);
    } else {
      loss = 0.5f * rank_loss(thres, union_max) + 0.5f * rank_loss(thres, inc_neg);
    }
    // fire-and-forget store to a distinct address per block -- removes the
    // 2048-deep same-address device-atomic serialization chain
    if (lane == 0) partial[row] = loss;
  }
}

__global__ void reduce_kernel(const float* __restrict__ partial,
                              float* __restrict__ out) {
  __shared__ float s_p[4];
  const int tid = threadIdx.x;  // 256
  float v = 0.0f;
#pragma unroll
  for (int k = 0; k < B_ROWS / 256; ++k) v += partial[tid + k * 256];
#pragma unroll
  for (int off = 32; off; off >>= 1) v += __shfl_xor(v, off);
  if ((tid & 63) == 0) s_p[tid >> 6] = v;
  __syncthreads();
  if (tid == 0) out[0] = s_p[0] + s_p[1] + s_p[2] + s_p[3];
}

extern "C" void kernel_launch(void* const* d_in, const int* in_sizes, int n_in,
                              void* d_out, int out_size, void* d_ws, size_t ws_size,
                              hipStream_t stream) {
  (void)in_sizes; (void)n_in; (void)out_size; (void)ws_size;
  const float* x = (const float*)d_in[0];
  const int* y = (const int*)d_in[1];
  const int* yn = (const int*)d_in[2];
  const void* gm = d_in[3];

  int* flag = (int*)d_ws;
  unsigned char* ws = (unsigned char*)d_ws;
  unsigned char* ws64 = ws + 64;
  float* partial = (float*)(ws + PARTIAL_OFF);

  probe_init_kernel<<<1, 1024, 0, stream>>>((const uint4*)gm, ws,
                                            (float*)d_out, flag);
  build_gid_kernel<<<(GM_BYTES + 255) / 256, 256, 0, stream>>>(gm, flag, ws);
  loss_kernel<<<B_ROWS, 256, 0, stream>>>(x, y, yn, ws64, partial);
  reduce_kernel<<<1, 256, 0, stream>>>(partial, (float*)d_out);
}

// Round 5
// 255.056 us; speedup vs baseline: 1.1091x; 1.0045x over previous
//
#include <hip/hip_runtime.h>
#include <stdint.h>

#define B_ROWS 2048
#define C_CLS  9605
#define L_GRP  20
#define GM_BYTES (L_GRP * C_CLS) /* 192100 */
#define REPSTRIDE 9728           /* multiple of 4, > C_CLS */
#define GID_REGION (4 * REPSTRIDE) /* 38912 B of gid copies at ws+64 */
#define NEG_BIG -3.0e38f

__device__ __forceinline__ float sigmoidf(float v) {
  return 1.0f / (1.0f + __expf(-v));
}

// our_rank_loss: d = x2-x1+0.05; s = sigmoid(10*d); d>0 ? 2*s : s
__device__ __forceinline__ float rank_loss(float x1, float x2) {
  float d = x2 - x1 + 0.05f;
  float s = 1.0f / (1.0f + __expf(-10.0f * d));
  return d > 0.0f ? 2.0f * s : s;
}

// order-preserving float<->uint mapping (unsigned atomicMax on floats)
__device__ __forceinline__ unsigned fmap(float f) {
  unsigned u = __float_as_uint(f);
  return (u & 0x80000000u) ? ~u : (u | 0x80000000u);
}
__device__ __forceinline__ float funmap(unsigned m) {
  unsigned u = (m & 0x80000000u) ? (m ^ 0x80000000u) : ~m;
  return __uint_as_float(u);
}

// ws layout: [0..63] flag ; [64 ...] 4 byte-shifted gid copies, copy m at
// ws + 64 + m*REPSTRIDE + m. Single-block kernel: zero d_out, 0xFF-init the
// gid region (uint4 fills), vector-count nonzero bytes of group_mask's first
// L*C bytes (1000 -> byte/bool layout; 250 int32 / 500 fp32 -> 4-byte).
__global__ void probe_init_kernel(const uint4* __restrict__ gm,
                                  unsigned char* __restrict__ ws,
                                  float* __restrict__ out,
                                  int* __restrict__ flag) {
  __shared__ int s_part[16];
  const int tid = threadIdx.x;  // 1024 threads
  if (tid == 0) out[0] = 0.0f;
  uint4* gfill = (uint4*)(ws + 64);  // ws+64 is 16B-aligned
  const unsigned F = 0xFFFFFFFFu;
  for (int i = tid; i < GID_REGION / 16; i += 1024)
    gfill[i] = make_uint4(F, F, F, F);
  int local = 0;
  const int nvec = GM_BYTES / 16;  // 12006 (tail = 4 bytes)
  for (int i = tid; i < nvec; i += 1024) {
    uint4 w = gm[i];
    unsigned a[4] = {w.x, w.y, w.z, w.w};
#pragma unroll
    for (int q = 0; q < 4; ++q) {
      local += ((a[q] & 0x000000FFu) != 0) + ((a[q] & 0x0000FF00u) != 0) +
               ((a[q] & 0x00FF0000u) != 0) + ((a[q] & 0xFF000000u) != 0);
    }
  }
  if (tid == 0) {
    const unsigned char* gb = (const unsigned char*)gm;
    for (int i = nvec * 16; i < GM_BYTES; ++i) local += (gb[i] != 0);
  }
#pragma unroll
  for (int off = 32; off; off >>= 1) local += __shfl_xor(local, off);
  if ((tid & 63) == 0) s_part[tid >> 6] = local;
  __syncthreads();
  if (tid == 0) {
    int tot = 0;
    for (int w = 0; w < 16; ++w) tot += s_part[w];
    *flag = tot;
  }
}

__global__ void build_gid_kernel(const void* gm, const int* __restrict__ flag,
                                 unsigned char* __restrict__ ws) {
  int i = blockIdx.x * blockDim.x + threadIdx.x;
  if (i >= GM_BYTES) return;
  const bool is_byte = (*flag > 600);
  bool m;
  if (is_byte) m = ((const unsigned char*)gm)[i] != 0;
  else         m = ((const unsigned int*)gm)[i] != 0u;
  if (m) {
    int l = i / C_CLS;
    int c = i - l * C_CLS;
    unsigned char* base = ws + 64;
#pragma unroll
    for (int r = 0; r < 4; ++r) base[r * REPSTRIDE + r + c] = (unsigned char)l;
  }
}

__global__ __launch_bounds__(256, 4) void loss_kernel(
    const float* __restrict__ x, const int* __restrict__ y,
    const int* __restrict__ yn, const unsigned char* __restrict__ ws64,
    float* __restrict__ out) {
  __shared__ unsigned s_gmax[L_GRP];
  __shared__ unsigned s_act, s_actn;
  __shared__ float s_wtop[4 * 11];
  const int tid = threadIdx.x;
  const int lane = tid & 63;
  const int wave = tid >> 6;
  const int row = blockIdx.x;  // grid = B_ROWS

  const size_t base = (size_t)row * C_CLS;
  const int mis = (int)(base & 3);
  const int peel = (4 - mis) & 3;
  const float* xr = x + base;
  const int* yr = y + base;
  const int* nr = yn + base;
  const unsigned char* gidc = ws64 + mis * REPSTRIDE + mis;  // gidc[c]=gid[c]

  if (tid < L_GRP) s_gmax[tid] = 0u;  // 0 < fmap(any real float)
  if (tid == 0) { s_act = 0u; s_actn = 0u; }
  __syncthreads();

  // top-11 of raw x, descending. Init 0.0f is safe: thres clamps at
  // sigmoid>=0.5 <=> x>=0, so any 11th value <=0 is equivalent to 0.
  float t[11];
#pragma unroll
  for (int i = 0; i < 11; ++i) t[i] = 0.0f;
  unsigned actL = 0u, actnL = 0u;

  auto ins = [&](float v) {
    if (v > t[10]) {  // sorted insert
      float a = v;
#pragma unroll
      for (int i = 0; i < 11; ++i) {
        float hi = fmaxf(t[i], a); a = fminf(t[i], a); t[i] = hi;
      }
    }
  };
  // lazy group max: plain LDS read, atomic only if improving (monotone up,
  // so a stale read is never too high -> safe)
  auto gmax_upd = [&](unsigned gk, float v) {
    unsigned fm = fmap(v);
    if (fm > s_gmax[gk]) atomicMax(&s_gmax[gk], fm);
  };
  auto edge = [&](int c) {  // scalar path for peel/tail elements
    float v = xr[c];
    ins(v);
    unsigned gk = gidc[c];
    if (gk < L_GRP) {
      gmax_upd(gk, v);
      unsigned bit = 1u << gk;
      if (yr[c] != 0) actL |= bit;
      if (nr[c] != 0) actnL |= bit;
    }
  };

  if (tid < peel) edge(tid);
  const int nvec = (C_CLS - peel) >> 2;
  const int tail0 = peel + (nvec << 2);
  if (tid < C_CLS - tail0) edge(tail0 + tid);

  const float4* x4 = (const float4*)(xr + peel);
  const int4* y4 = (const int4*)(yr + peel);
  const int4* n4 = (const int4*)(nr + peel);
  const unsigned* g4 = (const unsigned*)(gidc + peel);

  // per-quad processing (identical logic to round 3)
  auto quad = [&](float4 xv, int4 yv, int4 nv, unsigned gw) {
    // group-max path (~34% of quads contain a whitelisted element)
    if (gw != 0xFFFFFFFFu) {
      unsigned g0 = gw & 0xFFu, g1 = (gw >> 8) & 0xFFu,
               g2 = (gw >> 16) & 0xFFu, g3 = gw >> 24;
      if (g0 < L_GRP) gmax_upd(g0, xv.x);
      if (g1 < L_GRP) gmax_upd(g1, xv.y);
      if (g2 < L_GRP) gmax_upd(g2, xv.z);
      if (g3 < L_GRP) gmax_upd(g3, xv.w);
    }
    // active-bits path (rare: ~0.1% density)
    if (yv.x | yv.y | yv.z | yv.w | nv.x | nv.y | nv.z | nv.w) {
      const int yq[4] = {yv.x, yv.y, yv.z, yv.w};
      const int nq[4] = {nv.x, nv.y, nv.z, nv.w};
      const unsigned gq[4] = {gw & 0xFFu, (gw >> 8) & 0xFFu,
                              (gw >> 16) & 0xFFu, gw >> 24};
#pragma unroll
      for (int q = 0; q < 4; ++q) {
        if ((yq[q] | nq[q]) && gq[q] < L_GRP) {
          unsigned bit = 1u << gq[q];
          if (yq[q]) actL |= bit;
          if (nq[q]) actnL |= bit;
        }
      }
    }
    // top-11 insert, pre-gated on the 4-max
    float am = fmaxf(fmaxf(xv.x, xv.y), fmaxf(xv.z, xv.w));
    if (am > t[10]) { ins(xv.x); ins(xv.y); ins(xv.z); ins(xv.w); }
  };

  // ---- main loop: 4 strided iterations' loads batched UNCONDITIONALLY
  // before any processing -> ~16 loads (208 B/lane) in flight per wave ----
  int j = tid;
  for (; j + 768 < nvec; j += 1024) {
    float4 xa = x4[j];
    float4 xb = x4[j + 256];
    float4 xc = x4[j + 512];
    float4 xd = x4[j + 768];
    int4 ya = y4[j];
    int4 yb = y4[j + 256];
    int4 yc = y4[j + 512];
    int4 yd = y4[j + 768];
    int4 na = n4[j];
    int4 nb = n4[j + 256];
    int4 nc = n4[j + 512];
    int4 nd = n4[j + 768];
    unsigned ga = g4[j];
    unsigned gb = g4[j + 256];
    unsigned gc = g4[j + 512];
    unsigned gd = g4[j + 768];
    quad(xa, ya, na, ga);
    quad(xb, yb, nb, gb);
    quad(xc, yc, nc, gc);
    quad(xd, yd, nd, gd);
  }
  for (; j < nvec; j += 256) {
    quad(x4[j], y4[j], n4[j], g4[j]);
  }

  if (actL) atomicOr(&s_act, actL);    // rare (~1 positive/row)
  if (actnL) atomicOr(&s_actn, actnL);

  // wave top-11: 11 rounds of max-extract from 64 sorted per-lane lists
  float cur = t[0];
  float mr[11];
#pragma unroll
  for (int r = 0; r < 11; ++r) {
    float m = cur;
#pragma unroll
    for (int off = 32; off; off >>= 1) m = fmaxf(m, __shfl_xor(m, off));
    mr[r] = m;
    if (r < 10) {
      unsigned long long b = __ballot(cur == m);
      int leader = (int)(__ffsll(b) - 1);
      if (lane == leader) {
#pragma unroll
        for (int i = 0; i < 10; ++i) t[i] = t[i + 1];
        t[10] = NEG_BIG;
        cur = t[0];
      }
    }
  }
  if (lane == 0) {
#pragma unroll
    for (int r = 0; r < 11; ++r) s_wtop[wave * 11 + r] = mr[r];
  }
  __syncthreads();  // also publishes s_gmax / s_act / s_actn

  if (wave == 0) {
    // merge 4 waves' sorted top-11 (44 candidates): 11 extract rounds
    float v = (lane < 44) ? s_wtop[lane] : NEG_BIG;
    float eleventh = NEG_BIG;
#pragma unroll
    for (int r = 0; r < 11; ++r) {
      float m = v;
#pragma unroll
      for (int off = 32; off; off >>= 1) m = fmaxf(m, __shfl_xor(m, off));
      eleventh = m;
      if (r < 10) {
        unsigned long long b = __ballot(v == m);
        int leader = (int)(__ffsll(b) - 1);
        if (lane == leader) v = NEG_BIG;
      }
    }

    const unsigned aL = s_act, anL = s_actn;
    const bool has_gt = (aL != 0u);
    const int g = has_gt ? (__ffs(aL) - 1) : 0;  // argmax of bool = first
    const float thres = fmaxf(sigmoidf(eleventh), 0.5f);

    float union_max = NEG_BIG, gt_sg = 0.0f, inc_max = NEG_BIG, inc_neg = 0.0f;
#pragma unroll
    for (int l = 0; l < L_GRP; ++l) {
      float sg = sigmoidf(funmap(s_gmax[l]));
      union_max = fmaxf(union_max, sg);
      if (l == g) gt_sg = sg; else inc_max = fmaxf(inc_max, sg);
      if ((anL >> l) & 1u) inc_neg = fmaxf(inc_neg, sg);
    }
    inc_max = fmaxf(inc_max, 0.0f);
    inc_neg = fmaxf(inc_neg, 0.0f);

    float loss;
    if (has_gt) {
      loss = rank_loss(gt_sg, thres);
      if (inc_max > 0.0f) loss += 0.5f * rank_loss(thres, inc_max);
      loss += 0.5f * rank_loss(thres, (inc_neg > 0.0f) ? inc_neg : inc_max);
    } else {
      loss = 0.5f * rank_loss(thres, union_max) + 0.5f * rank_loss(thres, inc_neg);
    }
    if (lane == 0) atomicAdd(out, loss);
  }
}

extern "C" void kernel_launch(void* const* d_in, const int* in_sizes, int n_in,
                              void* d_out, int out_size, void* d_ws, size_t ws_size,
                              hipStream_t stream) {
  (void)in_sizes; (void)n_in; (void)out_size; (void)ws_size;
  const float* x = (const float*)d_in[0];
  const int* y = (const int*)d_in[1];
  const int* yn = (const int*)d_in[2];
  const void* gm = d_in[3];

  int* flag = (int*)d_ws;
  unsigned char* ws = (unsigned char*)d_ws;
  unsigned char* ws64 = ws + 64;

  probe_init_kernel<<<1, 1024, 0, stream>>>((const uint4*)gm, ws,
                                            (float*)d_out, flag);
  build_gid_kernel<<<(GM_BYTES + 255) / 256, 256, 0, stream>>>(gm, flag, ws);
  loss_kernel<<<B_ROWS, 256, 0, stream>>>(x, y, yn, ws64, (float*)d_out);
}